// Round 7
// baseline (309.244 us; speedup 1.0000x reference)
//
#include <hip/hip_runtime.h>
#include <hip/hip_fp16.h>

// CapsuleLayer dynamic routing — round 11: fused 3-round persistent kernel,
// hat recomputed per round (no hat storage).
// Round-10 post-mortem: hat-through-workspace = 283MB of HBM traffic (write
// 92MB @2.2TB/s = 47us + 2 reads ~43us each) = ~135us of the 147us total.
// Recompute is cheaper: W-stream 2.95MB/block/round from per-XCD L2 (Wc is
// L2-resident, shared by the XCD's 32 blocks) = 2.27GB aggregate / 34.5TB/s
// ~ 66us for all 3 rounds; VALU (~16us) hides under it. Thread-local softmax
// + the v1+v2 logit identity (b2 = b0 + <hat, v1+v2>) make rounds need only
// 160 floats of cross-round state -> all 3 rounds fuse into ONE kernel
// (block = one batch element, slice-scoped hat2 = 40 VGPRs, proven spill-free
// at VGPR_Count=68 in round 10). 2 launches total, no atomics, no hat ws.

#define IC 1152
#define IE 8
#define NC 10
#define DV 16
#define NB 256
#define NW (IC * NC * IE * DV)  // 1,474,560
#define SOUT (NC * DV)          // 160
#define NWAVE 12
#define TPB (NWAVE * 64)        // 768
#define NGPW 3                  // Gp groups per wave (36 = 12*3)

typedef _Float16 h2 __attribute__((ext_vector_type(2)));
union WChunk { int4 v; h2 p[4]; _Float16 h[8]; };
union XFrag { int4 v; h2 p[4]; };

#if defined(__has_builtin) && __has_builtin(__builtin_amdgcn_fdot2)
__device__ inline float fdot2(h2 a, h2 b, float c) {
    return __builtin_amdgcn_fdot2(a, b, c, false);
}
#else
__device__ inline float fdot2(h2 a, h2 b, float c) {
    return fmaf((float)a.x, (float)b.x, fmaf((float)a.y, (float)b.y, c));
}
#endif

// W fp32 [i][j][e][d] -> fp16 chunks Wc[((Gp*10+j)*8+k)*64 + lane], where
// lane = h*32+r, i = Gp*32+r, d = h*8+k; chunk holds e=0..7 halves of W[i,j,:,d].
__global__ void wprep_kernel(const float* __restrict__ W, int4* __restrict__ Wc) {
    const int t = blockIdx.x * blockDim.x + threadIdx.x;
    if (t >= NW / 8) return;
    const int lane = t & 63;
    const int h = lane >> 5, r = lane & 31;
    const int k = (t >> 6) & 7;
    const int r2 = t >> 9;  // Gp*10 + j
    const int j = r2 % NC, Gp = r2 / NC;
    const int i = Gp * 32 + r;
    const int d = h * 8 + k;
    const float* src = W + ((size_t)(i * NC + j) * IE) * DV + d;  // e-stride DV
    WChunk c;
#pragma unroll
    for (int e = 0; e < IE; ++e) c.h[e] = (_Float16)src[(size_t)e * DV];
    Wc[t] = c.v;
}

// Fused 3-round routing. Block = one batch element b; wave w owns Gp in
// {3w..3w+2}; lane g = h*32+r covers row i=Gp*32+r, d-half h = d/8.
// Per (round, Gp-slice): recompute hat for all 10 j (40 h2 regs, slice-scoped,
// promotes cleanly), thread-local softmax over j (logits use the running
// v-sum: b_r = b0 + <hat, sum_{r'<r} v_{r'}>), butterfly-reduce s into the
// wave's exclusive LDS slab; per round: reduce slabs + squash + update vc/v2s.
__global__ __launch_bounds__(TPB) void caps_kernel(
    const float* __restrict__ X,     // [B, IC, IE] fp32
    const int4* __restrict__ Wc,     // coalesced fp16 W (see wprep)
    const float* __restrict__ bias,  // [IC*NC] fp32
    float* __restrict__ out)         // [B, NC, DV]
{
    __shared__ float s_part[NWAVE * SOUT];      // per-wave exclusive slabs (7.5KB)
    __shared__ float vc[SOUT];                  // running v1+v2 (f32)
    __shared__ __align__(16) h2 v2s[SOUT / 2];  // running v packed for fdot2

    const int b = blockIdx.x;
    const int tid = threadIdx.x;
    const int w = tid >> 6;  // wave 0..11
    const int g = tid & 63;
    const int h = g >> 5;    // d-half: d = h*8 + k
    const int r = g & 31;    // row within 32-row group

    // zero own slab (wave-private; each wave accumulates only into its own)
    for (int idx = g; idx < SOUT; idx += 64) s_part[w * SOUT + idx] = 0.f;

    for (int rd = 0; rd < 3; ++rd) {
#pragma unroll
        for (int gl = 0; gl < NGPW; ++gl) {
            const int Gp = NGPW * w + gl;
            const int i = Gp * 32 + r;

            // ---- X row (L1/L2-resident after round 0), packed to h2 ----
            XFrag xu;
            {
                const float4* xr = (const float4*)(X + ((size_t)b * IC + i) * IE);
                const float4 x0 = xr[0], x1 = xr[1];
                xu.p[0] = h2{(_Float16)x0.x, (_Float16)x0.y};
                xu.p[1] = h2{(_Float16)x0.z, (_Float16)x0.w};
                xu.p[2] = h2{(_Float16)x1.x, (_Float16)x1.y};
                xu.p[3] = h2{(_Float16)x1.z, (_Float16)x1.w};
            }

            // ---- hat for all 10 j of this slice (40 h2 regs, slice-scoped) ----
            h2 hat2[NC][4];
#pragma unroll
            for (int j = 0; j < NC; ++j) {
                const int4* wp = Wc + ((size_t)(Gp * NC + j)) * 512 + g;
                WChunk wk[4];
                float hat[8];
#pragma unroll
                for (int k = 0; k < 4; ++k) wk[k].v = wp[k * 64];
#pragma unroll
                for (int k = 0; k < 4; ++k) {
                    float a = 0.f;
#pragma unroll
                    for (int q = 0; q < 4; ++q) a = fdot2(xu.p[q], wk[k].p[q], a);
                    hat[k] = a;
                }
#pragma unroll
                for (int k = 0; k < 4; ++k) wk[k].v = wp[(k + 4) * 64];
#pragma unroll
                for (int k = 0; k < 4; ++k) {
                    float a = 0.f;
#pragma unroll
                    for (int q = 0; q < 4; ++q) a = fdot2(xu.p[q], wk[k].p[q], a);
                    hat[k + 4] = a;
                }
#pragma unroll
                for (int q = 0; q < 4; ++q)
                    hat2[j][q] = h2{(_Float16)hat[2 * q], (_Float16)hat[2 * q + 1]};
            }

            // ---- logits + THREAD-LOCAL softmax over j ----
            float c[NC];
            {
                float Z = 0.f;
#pragma unroll
                for (int j = 0; j < NC; ++j) {
                    float lt = bias[i * NC + j];
                    if (rd > 0) {
                        XFrag vv;
                        vv.v = *(const int4*)(v2s + (j * 8 + h * 4));
                        float ah = 0.f;
#pragma unroll
                        for (int q = 0; q < 4; ++q) ah = fdot2(hat2[j][q], vv.p[q], ah);
                        lt += ah + __shfl_xor(ah, 32);  // combine d-halves
                    }
                    const float e = __expf(lt);
                    c[j] = e;
                    Z += e;
                }
                const float rz = 1.f / Z;
#pragma unroll
                for (int j = 0; j < NC; ++j) c[j] *= rz;
            }

            // ---- weighted sum: butterfly over 32 r-lanes per j, += wave slab ----
#pragma unroll
            for (int j = 0; j < NC; ++j) {
                float s8[8];
#pragma unroll
                for (int q = 0; q < 4; ++q) {
                    s8[2 * q]     = c[j] * (float)hat2[j][q].x;
                    s8[2 * q + 1] = c[j] * (float)hat2[j][q].y;
                }
                float t4[4];
#pragma unroll
                for (int d = 0; d < 4; ++d) {
                    const bool hi = (r & 16);
                    const float mine = hi ? s8[d + 4] : s8[d];
                    const float send = hi ? s8[d] : s8[d + 4];
                    t4[d] = mine + __shfl_xor(send, 16);
                }
                float t2[2];
#pragma unroll
                for (int d = 0; d < 2; ++d) {
                    const bool hi = (r & 8);
                    const float mine = hi ? t4[d + 2] : t4[d];
                    const float send = hi ? t4[d] : t4[d + 2];
                    t2[d] = mine + __shfl_xor(send, 8);
                }
                float t1;
                {
                    const bool hi = (r & 4);
                    const float mine = hi ? t2[1] : t2[0];
                    const float send = hi ? t2[0] : t2[1];
                    t1 = mine + __shfl_xor(send, 4);
                }
                t1 += __shfl_xor(t1, 2);
                t1 += __shfl_xor(t1, 1);
                if ((r & 3) == 0) {
                    const int dl = (r >> 2) & 7;  // bit map: r4->d2, r3->d1, r2->d0
                    s_part[w * SOUT + j * DV + h * 8 + dl] += t1;
                }
            }
        }
        __syncthreads();  // slabs complete

        // ---- reduce slabs + squash; update running v (or write output) ----
        if (tid < SOUT) {
            float sv = 0.f;
#pragma unroll
            for (int ww = 0; ww < NWAVE; ++ww) sv += s_part[ww * SOUT + tid];
            float s2 = sv * sv;
#pragma unroll
            for (int mk = 8; mk >= 1; mk >>= 1) s2 += __shfl_xor(s2, mk, 16);
            const float scale = sqrtf(s2) / (1.f + s2);
            const float vv = scale * sv;
            if (rd == 2) {
                out[(size_t)b * SOUT + tid] = vv;
            } else {
                const float vcum = (rd == 0) ? vv : (vc[tid] + vv);
                vc[tid] = vcum;
                const float oth = __shfl_xor(vcum, 1);
                if (!(tid & 1)) v2s[tid >> 1] = h2{(_Float16)vcum, (_Float16)oth};
            }
        }
        __syncthreads();  // v2s visible; slab reads done

        if (rd < 2) {  // re-zero own slab for the next round
            for (int idx = g; idx < SOUT; idx += 64) s_part[w * SOUT + idx] = 0.f;
        }
    }
}

extern "C" void kernel_launch(void* const* d_in, const int* in_sizes, int n_in,
                              void* d_out, int out_size, void* d_ws, size_t ws_size,
                              hipStream_t stream) {
    const float* X = (const float*)d_in[0];     // [256,1152,8]
    const float* W = (const float*)d_in[1];     // [1152,10,8,16]
    const float* bias = (const float*)d_in[2];  // [1,1152,10]
    float* out = (float*)d_out;

    int4* Wc = (int4*)d_ws;  // ws: Wc only (2.95 MB)

    wprep_kernel<<<dim3(720), dim3(256), 0, stream>>>(W, Wc);
    caps_kernel<<<dim3(NB), dim3(TPB), 0, stream>>>(X, Wc, bias, out);
}